// Round 8
// baseline (300.836 us; speedup 1.0000x reference)
//
#include <hip/hip_runtime.h>

#define D 128

typedef __attribute__((ext_vector_type(8))) short bf16x8;
typedef __attribute__((ext_vector_type(4))) float f32x4;
typedef __attribute__((ext_vector_type(2))) float f32x2;
typedef __attribute__((ext_vector_type(2))) uint  u32x2;

__device__ __forceinline__ ushort f2bf(float f) {   // round-to-nearest-even
    unsigned u = __float_as_uint(f);
    u += 0x7fffu + ((u >> 16) & 1u);
    return (ushort)(u >> 16);
}
__device__ __forceinline__ float bf2f(ushort h) {
    return __uint_as_float(((unsigned)h) << 16);
}

// ---------------------------------------------------------------------------
// XW(bf16) = X(fp32) @ W(fp32) + fused row_ptr build. (unchanged, r6-proven)
// ---------------------------------------------------------------------------
__global__ __launch_bounds__(256) void gemm_mfma(const float* __restrict__ X,
                                                 const float* __restrict__ W,
                                                 const int* __restrict__ rows,
                                                 int E,
                                                 ushort* __restrict__ XW,
                                                 int* __restrict__ rp, int M) {
    __shared__ ushort Wl[16384];   // 32KB, fragment-ordered, linear

    const int t = threadIdx.x;

    {   // fused row_ptr: thread g does lower_bound(rows, g), g in [0, M]
        const int g = blockIdx.x * 256 + t;
        if (g <= M) {
            int lo = 0, hi = E;
            while (lo < hi) {
                int mid = (lo + hi) >> 1;
                if (rows[mid] < g) lo = mid + 1; else hi = mid;
            }
            rp[g] = lo;
        }
    }

    {   // W conversion into fragment-ordered LDS
        const int c = t & 127, half = t >> 7;
        const int jt = c >> 4;
#pragma unroll
        for (int g = 0; g < 8; ++g) {
            const int k8   = half + g * 2;
            const int ks   = k8 >> 2;
            const int lsub = (k8 & 3) * 16 + (c & 15);
            uint4 pk;
            ushort tmp[8];
#pragma unroll
            for (int j = 0; j < 8; ++j)
                tmp[j] = f2bf(W[(k8 * 8 + j) * D + c]);
            pk.x = (uint)tmp[0] | ((uint)tmp[1] << 16);
            pk.y = (uint)tmp[2] | ((uint)tmp[3] << 16);
            pk.z = (uint)tmp[4] | ((uint)tmp[5] << 16);
            pk.w = (uint)tmp[6] | ((uint)tmp[7] << 16);
            *(uint4*)&Wl[(((jt * 4 + ks) * 64) + lsub) * 8] = pk;
        }
    }

    const int lane = t & 63, wid = t >> 6;
    const int r0 = blockIdx.x * 64 + wid * 16;

    int arow = r0 + (lane & 15);
    if (arow >= M) arow = M - 1;
    const float* xp = X + (size_t)arow * D + ((lane >> 4) * 8);

    bf16x8 xf[4];
#pragma unroll
    for (int ks = 0; ks < 4; ++ks) {
        float4 f0 = *(const float4*)(xp + ks * 32);
        float4 f1 = *(const float4*)(xp + ks * 32 + 4);
        bf16x8 av;
        av[0] = (short)f2bf(f0.x); av[1] = (short)f2bf(f0.y);
        av[2] = (short)f2bf(f0.z); av[3] = (short)f2bf(f0.w);
        av[4] = (short)f2bf(f1.x); av[5] = (short)f2bf(f1.y);
        av[6] = (short)f2bf(f1.z); av[7] = (short)f2bf(f1.w);
        xf[ks] = av;
    }

    __syncthreads();

    const bf16x8* wl = (const bf16x8*)Wl + lane;

    f32x4 acc[8];
#pragma unroll
    for (int jt = 0; jt < 8; ++jt) acc[jt] = (f32x4){0.f, 0.f, 0.f, 0.f};

#pragma unroll
    for (int jt = 0; jt < 8; ++jt)
#pragma unroll
        for (int ks = 0; ks < 4; ++ks) {
            bf16x8 w = wl[(jt * 4 + ks) * 64];
            acc[jt] = __builtin_amdgcn_mfma_f32_16x16x32_bf16(w, xf[ks],
                                                              acc[jt], 0, 0, 0);
        }

    const int row = r0 + (lane & 15);
    if (row < M) {
        uint* dst = (uint*)XW + (size_t)row * 64 + (lane >> 4) * 2;
#pragma unroll
        for (int jt = 0; jt < 8; ++jt) {
            u32x2 pv;
            pv[0] = (uint)f2bf(acc[jt][0]) | ((uint)f2bf(acc[jt][1]) << 16);
            pv[1] = (uint)f2bf(acc[jt][2]) | ((uint)f2bf(acc[jt][3]) << 16);
            *(u32x2*)(dst + jt * 8) = pv;
        }
    }
}

// ---------------------------------------------------------------------------
// Reorg: partition each row's edges into P=4 col-phases.
// One wave per row; two-pass ballot compaction; (col,val) packed as i64:
//   low 32 = col, high 32 = val bits.
// Phase assignment (float mul) only affects ORDER, never the math.
// ---------------------------------------------------------------------------
__global__ __launch_bounds__(256) void reorg_edges(const int* __restrict__ rp,
                                                   const int* __restrict__ cols,
                                                   const float* __restrict__ vals,
                                                   long long* __restrict__ colv,
                                                   int4* __restrict__ off,
                                                   int N, float inv_psize) {
    const int lane = threadIdx.x & 63;
    const int r = blockIdx.x * 4 + (threadIdx.x >> 6);
    if (r >= N) return;
    const int s = rp[r], e = rp[r + 1];

    int cnt0 = 0, cnt1 = 0, cnt2 = 0;
    for (int base = s; base < e; base += 64) {
        const bool act = (base + lane) < e;
        int c = act ? cols[base + lane] : 0;
        int ph = (int)((float)c * inv_psize); ph = ph > 3 ? 3 : ph;
        cnt0 += __popcll(__ballot(act && ph == 0));
        cnt1 += __popcll(__ballot(act && ph == 1));
        cnt2 += __popcll(__ballot(act && ph == 2));
    }
    const int st0 = s, st1 = st0 + cnt0, st2 = st1 + cnt1, st3 = st2 + cnt2;
    if (lane == 0) off[r] = make_int4(st0, st1, st2, st3);

    int d0 = 0, d1 = 0, d2 = 0, d3 = 0;
    for (int base = s; base < e; base += 64) {
        const bool act = (base + lane) < e;
        int   c = act ? cols[base + lane] : 0;
        float v = act ? vals[base + lane] : 0.f;
        int ph = (int)((float)c * inv_psize); ph = ph > 3 ? 3 : ph;
        unsigned long long b0 = __ballot(act && ph == 0);
        unsigned long long b1 = __ballot(act && ph == 1);
        unsigned long long b2 = __ballot(act && ph == 2);
        unsigned long long b3 = __ballot(act && ph == 3);
        unsigned long long lmlt = (1ull << lane) - 1ull;
        unsigned long long bm = ph == 0 ? b0 : ph == 1 ? b1 : ph == 2 ? b2 : b3;
        int stp = ph == 0 ? st0 : ph == 1 ? st1 : ph == 2 ? st2 : st3;
        int dnp = ph == 0 ? d0  : ph == 1 ? d1  : ph == 2 ? d2  : d3;
        if (act) {
            int pos = stp + dnp + __popcll(bm & lmlt);
            colv[pos] = (long long)(unsigned)c |
                        ((long long)(unsigned)__float_as_uint(v) << 32);
        }
        d0 += __popcll(b0); d1 += __popcll(b1);
        d2 += __popcll(b2); d3 += __popcll(b3);
    }
}

// ---------------------------------------------------------------------------
// Phased SpMM: block owns 24 rows (6/wave); accumulators live in registers
// across all 4 col-phases; per-phase the device-wide gather footprint is
// ~1/4 of XW. Clamped unroll-4 gathers (dummy = last in-phase entry, v=0).
// ---------------------------------------------------------------------------
#define RW 6
#define BR 24
__global__ __launch_bounds__(256, 4) void spmm_phased(
        const ushort* __restrict__ XW, const int* __restrict__ rp,
        const int4* __restrict__ off, const long long* __restrict__ colv,
        float* __restrict__ out, int N) {
    const int lane = threadIdx.x & 63;
    const int wid  = threadIdx.x >> 6;
    const int r0 = blockIdx.x * BR + wid * RW;
    const uint* base = (const uint*)XW;

    float ax[RW], ay[RW];
#pragma unroll
    for (int k = 0; k < RW; ++k) { ax[k] = 0.f; ay[k] = 0.f; }

#pragma unroll
    for (int p = 0; p < 4; ++p) {
#pragma unroll
        for (int k = 0; k < RW; ++k) {
            const int r = r0 + k;
            if (r >= N) continue;
            const int4 o = off[r];
            const int s = p == 0 ? o.x : p == 1 ? o.y : p == 2 ? o.z : o.w;
            const int e = p == 3 ? rp[r + 1] : (p == 0 ? o.y : p == 1 ? o.z : o.w);
            float axk = ax[k], ayk = ay[k];
            for (int i = s; i < e; i += 4) {
                long long cv[4];
#pragma unroll
                for (int q = 0; q < 4; ++q) {
                    int idx = i + q; idx = idx < e ? idx : e - 1;
                    cv[q] = __builtin_nontemporal_load(&colv[idx]);
                }
                uint u[4];
#pragma unroll
                for (int q = 0; q < 4; ++q)
                    u[q] = base[(size_t)(uint)(cv[q] & 0xffffffffll) * 64 + lane];
#pragma unroll
                for (int q = 0; q < 4; ++q) {
                    float v = (i + q < e)
                              ? __uint_as_float((uint)(cv[q] >> 32)) : 0.f;
                    axk += v * bf2f((ushort)(u[q] & 0xffff));
                    ayk += v * bf2f((ushort)(u[q] >> 16));
                }
            }
            ax[k] = axk; ay[k] = ayk;
        }
        __syncthreads();   // soft cohort alignment between phases
    }

#pragma unroll
    for (int k = 0; k < RW; ++k) {
        const int r = r0 + k;
        if (r < N) {
            f32x2 o2; o2[0] = ax[k]; o2[1] = ay[k];
            __builtin_nontemporal_store(o2, (f32x2*)out + (size_t)r * 64 + lane);
        }
    }
}

// ---------------------------------------------------------------------------
// Fallback SpMM (r6, proven): used if ws_size can't hold the reorg buffers.
// ---------------------------------------------------------------------------
__global__ __launch_bounds__(256) void spmm_csr(const ushort* __restrict__ XW,
                                                const int* __restrict__ rp,
                                                const int* __restrict__ cols,
                                                const float* __restrict__ vals,
                                                float* __restrict__ out, int N) {
    const int lane = threadIdx.x & 63;
    const int ra = blockIdx.x * 8 + (threadIdx.x >> 6) * 2;
    if (ra >= N) return;
    const bool has_b = (ra + 1) < N;

    const int sa = rp[ra];
    const int ea = rp[ra + 1];
    const int eb = has_b ? rp[ra + 2] : ea;

    const uint* base = (const uint*)XW;
    float axa = 0.f, aya = 0.f, axb = 0.f, ayb = 0.f;
    int ia = sa, ib = ea;

    while (ia + 4 <= ea && ib + 4 <= eb) {
        int c0[4], c1[4]; float v0[4], v1[4]; uint u0[4], u1[4];
#pragma unroll
        for (int q = 0; q < 4; ++q) {
            c0[q] = __builtin_nontemporal_load(&cols[ia + q]);
            c1[q] = __builtin_nontemporal_load(&cols[ib + q]);
            v0[q] = __builtin_nontemporal_load(&vals[ia + q]);
            v1[q] = __builtin_nontemporal_load(&vals[ib + q]);
        }
#pragma unroll
        for (int q = 0; q < 4; ++q) {
            u0[q] = base[(size_t)c0[q] * 64 + lane];
            u1[q] = base[(size_t)c1[q] * 64 + lane];
        }
#pragma unroll
        for (int q = 0; q < 4; ++q) {
            axa += v0[q] * bf2f((ushort)(u0[q] & 0xffff));
            aya += v0[q] * bf2f((ushort)(u0[q] >> 16));
            axb += v1[q] * bf2f((ushort)(u1[q] & 0xffff));
            ayb += v1[q] * bf2f((ushort)(u1[q] >> 16));
        }
        ia += 4; ib += 4;
    }
    for (; ia < ea; ++ia) {
        int c = cols[ia]; float v = vals[ia];
        uint u = base[(size_t)c * 64 + lane];
        axa += v * bf2f((ushort)(u & 0xffff));
        aya += v * bf2f((ushort)(u >> 16));
    }
    for (; ib < eb; ++ib) {
        int c = cols[ib]; float v = vals[ib];
        uint u = base[(size_t)c * 64 + lane];
        axb += v * bf2f((ushort)(u & 0xffff));
        ayb += v * bf2f((ushort)(u >> 16));
    }

    f32x2 oa; oa[0] = axa; oa[1] = aya;
    __builtin_nontemporal_store(oa, (f32x2*)out + (size_t)ra * 64 + lane);
    if (has_b) {
        f32x2 ob; ob[0] = axb; ob[1] = ayb;
        __builtin_nontemporal_store(ob, (f32x2*)out + (size_t)(ra + 1) * 64 + lane);
    }
}

// ---------------------------------------------------------------------------
extern "C" void kernel_launch(void* const* d_in, const int* in_sizes, int n_in,
                              void* d_out, int out_size, void* d_ws, size_t ws_size,
                              hipStream_t stream) {
    const float* X    = (const float*)d_in[0];
    const float* W    = (const float*)d_in[1];
    const int*   rows = (const int*)d_in[2];
    const int*   cols = (const int*)d_in[3];
    const float* vals = (const float*)d_in[4];
    float*       out  = (float*)d_out;

    const int M = in_sizes[0] / D;      // 100000 nodes
    const int E = in_sizes[2];          // 1600000 edges

    // Workspace layout:
    //   XW bf16[M*128] | rp int[M+1] (16B-aligned) | off int4[M] | colv i64[E]
    char* ws = (char*)d_ws;
    size_t o_xw   = 0;
    size_t o_rp   = o_xw + (size_t)M * D * sizeof(ushort);
    size_t o_off  = (o_rp + (size_t)(M + 1) * sizeof(int) + 15) & ~(size_t)15;
    size_t o_colv = o_off + (size_t)M * sizeof(int4);
    size_t need   = o_colv + (size_t)E * sizeof(long long);

    ushort*    XWb  = (ushort*)(ws + o_xw);
    int*       rp   = (int*)(ws + o_rp);
    int4*      off  = (int4*)(ws + o_off);
    long long* colv = (long long*)(ws + o_colv);

    gemm_mfma<<<(M + 63) / 64, 256, 0, stream>>>(X, W, rows, E, XWb, rp, M);

    if (ws_size >= need) {
        const float inv_psize = 1.0f / (float)((M + 3) / 4);
        reorg_edges<<<(M + 3) / 4, 256, 0, stream>>>(rp, cols, vals, colv, off,
                                                     M, inv_psize);
        spmm_phased<<<(M + BR - 1) / BR, 256, 0, stream>>>(XWb, rp, off, colv,
                                                           out, M);
    } else {
        spmm_csr<<<(M + 7) / 8, 256, 0, stream>>>(XWb, rp, cols, vals, out, M);
    }
}

// Round 12
// 229.633 us; speedup vs baseline: 1.3101x; 1.3101x over previous
//
#include <hip/hip_runtime.h>

#define D 128

typedef __attribute__((ext_vector_type(8))) short bf16x8;
typedef __attribute__((ext_vector_type(4))) float f32x4;
typedef __attribute__((ext_vector_type(2))) float f32x2;
typedef __attribute__((ext_vector_type(2))) uint  u32x2;

__device__ __forceinline__ ushort f2bf(float f) {   // round-to-nearest-even
    unsigned u = __float_as_uint(f);
    u += 0x7fffu + ((u >> 16) & 1u);
    return (ushort)(u >> 16);
}
__device__ __forceinline__ float bf2f(ushort h) {
    return __uint_as_float(((unsigned)h) << 16);
}

// ---------------------------------------------------------------------------
// Prep kernel (block-role partitioned):
//  * all blocks: stream-convert X fp32 -> Xb bf16 (8 elems/thread, coalesced)
//  * blocks [0,64):   also convert W -> fragment-ordered Wf (r4-verified map)
//  * blocks [64,64+rb): also build row_ptr via binary search (r6-verified)
// ---------------------------------------------------------------------------
__global__ __launch_bounds__(256) void prep(const float* __restrict__ X,
                                            const float* __restrict__ W,
                                            const int* __restrict__ rows,
                                            ushort* __restrict__ Xb,
                                            ushort* __restrict__ Wf,
                                            int* __restrict__ rp,
                                            int M, int E, int nXchunks) {
    const int b = blockIdx.x, t = threadIdx.x;

    // --- X convert: chunk of 8 floats -> bf16x8 ---
    const int idx8 = b * 256 + t;
    if (idx8 < nXchunks) {
        const float4 f0 = *(const float4*)(X + (size_t)idx8 * 8);
        const float4 f1 = *(const float4*)(X + (size_t)idx8 * 8 + 4);
        bf16x8 o;
        o[0] = (short)f2bf(f0.x); o[1] = (short)f2bf(f0.y);
        o[2] = (short)f2bf(f0.z); o[3] = (short)f2bf(f0.w);
        o[4] = (short)f2bf(f1.x); o[5] = (short)f2bf(f1.y);
        o[6] = (short)f2bf(f1.z); o[7] = (short)f2bf(f1.w);
        *(bf16x8*)(Xb + (size_t)idx8 * 8) = o;
    }

    // --- W convert into fragment order (r4-verified mapping) ---
    if (b < 64) {
        const int idx = b * 256 + t;        // 0..16383
        const int j    = idx & 7;
        const int lane = (idx >> 3) & 63;
        const int f    = idx >> 9;          // jt*4 + ks
        const int jt = f >> 2, ks = f & 3;
        const int col = jt * 16 + (lane & 15);
        const int k   = ks * 32 + ((lane >> 4) * 8) + j;
        Wf[idx] = f2bf(W[k * D + col]);
    }

    // --- row_ptr: g = lower_bound(rows, g) ---
    const int g = (b - 64) * 256 + t;
    if (b >= 64 && g <= M) {
        int lo = 0, hi = E;
        while (lo < hi) {
            int mid = (lo + hi) >> 1;
            if (rows[mid] < g) lo = mid + 1; else hi = mid;
        }
        rp[g] = lo;
    }
}

// ---------------------------------------------------------------------------
// Lean GEMM: XW(bf16) = Xb(bf16) @ W via mfma_f32_16x16x32_bf16, operands
// swapped (A=Wf frag from global/L1, B=X frag): D: lane&15 = XW row,
// (lane>>4)*4+reg = 4 consecutive XW cols. Zero conversion VALU in-loop.
// ---------------------------------------------------------------------------
__global__ __launch_bounds__(256) void gemm_lean(const ushort* __restrict__ Xb,
                                                 const ushort* __restrict__ Wf,
                                                 ushort* __restrict__ XW, int M) {
    const int t = threadIdx.x, lane = t & 63, wid = t >> 6;
    const int r0 = blockIdx.x * 64 + wid * 16;

    int arow = r0 + (lane & 15);
    if (arow >= M) arow = M - 1;                 // clamp; stores guarded
    const ushort* xp = Xb + (size_t)arow * D + ((lane >> 4) * 8);

    bf16x8 xf[4];
#pragma unroll
    for (int ks = 0; ks < 4; ++ks)
        xf[ks] = *(const bf16x8*)(xp + ks * 32);   // 16B aligned loads

    const bf16x8* wf = (const bf16x8*)Wf + lane;   // + (jt*4+ks)*64

    f32x4 acc[8];
#pragma unroll
    for (int jt = 0; jt < 8; ++jt) acc[jt] = (f32x4){0.f, 0.f, 0.f, 0.f};

#pragma unroll
    for (int jt = 0; jt < 8; ++jt)
#pragma unroll
        for (int ks = 0; ks < 4; ++ks) {
            bf16x8 w = wf[(jt * 4 + ks) * 64];     // 1KB coalesced, L1-hot
            acc[jt] = __builtin_amdgcn_mfma_f32_16x16x32_bf16(w, xf[ks],
                                                              acc[jt], 0, 0, 0);
        }

    const int row = r0 + (lane & 15);
    if (row < M) {
        uint* dst = (uint*)XW + (size_t)row * 64 + (lane >> 4) * 2;
#pragma unroll
        for (int jt = 0; jt < 8; ++jt) {
            u32x2 pv;
            pv[0] = (uint)f2bf(acc[jt][0]) | ((uint)f2bf(acc[jt][1]) << 16);
            pv[1] = (uint)f2bf(acc[jt][2]) | ((uint)f2bf(acc[jt][3]) << 16);
            *(u32x2*)(dst + jt * 8) = pv;
        }
    }
}

// ---------------------------------------------------------------------------
// Fallback GEMM (r6-proven, fused conversion+search) if ws can't hold Xb.
// ---------------------------------------------------------------------------
__global__ __launch_bounds__(256) void gemm_fused(const float* __restrict__ X,
                                                  const float* __restrict__ W,
                                                  const int* __restrict__ rows,
                                                  int E,
                                                  ushort* __restrict__ XW,
                                                  int* __restrict__ rp, int M) {
    __shared__ ushort Wl[16384];

    const int t = threadIdx.x;
    {
        const int g = blockIdx.x * 256 + t;
        if (g <= M) {
            int lo = 0, hi = E;
            while (lo < hi) {
                int mid = (lo + hi) >> 1;
                if (rows[mid] < g) lo = mid + 1; else hi = mid;
            }
            rp[g] = lo;
        }
    }
    {
        const int c = t & 127, half = t >> 7;
        const int jt = c >> 4;
#pragma unroll
        for (int g = 0; g < 8; ++g) {
            const int k8   = half + g * 2;
            const int ks   = k8 >> 2;
            const int lsub = (k8 & 3) * 16 + (c & 15);
            uint4 pk;
            ushort tmp[8];
#pragma unroll
            for (int j = 0; j < 8; ++j)
                tmp[j] = f2bf(W[(k8 * 8 + j) * D + c]);
            pk.x = (uint)tmp[0] | ((uint)tmp[1] << 16);
            pk.y = (uint)tmp[2] | ((uint)tmp[3] << 16);
            pk.z = (uint)tmp[4] | ((uint)tmp[5] << 16);
            pk.w = (uint)tmp[6] | ((uint)tmp[7] << 16);
            *(uint4*)&Wl[(((jt * 4 + ks) * 64) + lsub) * 8] = pk;
        }
    }

    const int lane = t & 63, wid = t >> 6;
    const int r0 = blockIdx.x * 64 + wid * 16;

    int arow = r0 + (lane & 15);
    if (arow >= M) arow = M - 1;
    const float* xp = X + (size_t)arow * D + ((lane >> 4) * 8);

    bf16x8 xf[4];
#pragma unroll
    for (int ks = 0; ks < 4; ++ks) {
        float4 f0 = *(const float4*)(xp + ks * 32);
        float4 f1 = *(const float4*)(xp + ks * 32 + 4);
        bf16x8 av;
        av[0] = (short)f2bf(f0.x); av[1] = (short)f2bf(f0.y);
        av[2] = (short)f2bf(f0.z); av[3] = (short)f2bf(f0.w);
        av[4] = (short)f2bf(f1.x); av[5] = (short)f2bf(f1.y);
        av[6] = (short)f2bf(f1.z); av[7] = (short)f2bf(f1.w);
        xf[ks] = av;
    }

    __syncthreads();

    const bf16x8* wl = (const bf16x8*)Wl + lane;

    f32x4 acc[8];
#pragma unroll
    for (int jt = 0; jt < 8; ++jt) acc[jt] = (f32x4){0.f, 0.f, 0.f, 0.f};

#pragma unroll
    for (int jt = 0; jt < 8; ++jt)
#pragma unroll
        for (int ks = 0; ks < 4; ++ks) {
            bf16x8 w = wl[(jt * 4 + ks) * 64];
            acc[jt] = __builtin_amdgcn_mfma_f32_16x16x32_bf16(w, xf[ks],
                                                              acc[jt], 0, 0, 0);
        }

    const int row = r0 + (lane & 15);
    if (row < M) {
        uint* dst = (uint*)XW + (size_t)row * 64 + (lane >> 4) * 2;
#pragma unroll
        for (int jt = 0; jt < 8; ++jt) {
            u32x2 pv;
            pv[0] = (uint)f2bf(acc[jt][0]) | ((uint)f2bf(acc[jt][1]) << 16);
            pv[1] = (uint)f2bf(acc[jt][2]) | ((uint)f2bf(acc[jt][3]) << 16);
            *(u32x2*)(dst + jt * 8) = pv;
        }
    }
}

// ---------------------------------------------------------------------------
// CSR SpMM (r6-proven): two rows per wave, joint unroll-4 = 8 gathers in
// flight. Lane owns 2 bf16 cols (4B gather/lane, 256B/edge). NT streams.
// ---------------------------------------------------------------------------
__global__ __launch_bounds__(256) void spmm_csr(const ushort* __restrict__ XW,
                                                const int* __restrict__ rp,
                                                const int* __restrict__ cols,
                                                const float* __restrict__ vals,
                                                float* __restrict__ out, int N) {
    const int lane = threadIdx.x & 63;
    const int ra = blockIdx.x * 8 + (threadIdx.x >> 6) * 2;
    if (ra >= N) return;
    const bool has_b = (ra + 1) < N;

    const int sa = rp[ra];
    const int ea = rp[ra + 1];
    const int eb = has_b ? rp[ra + 2] : ea;

    const uint* base = (const uint*)XW;
    float axa = 0.f, aya = 0.f, axb = 0.f, ayb = 0.f;
    int ia = sa, ib = ea;

    while (ia + 4 <= ea && ib + 4 <= eb) {
        int c0[4], c1[4]; float v0[4], v1[4]; uint u0[4], u1[4];
#pragma unroll
        for (int q = 0; q < 4; ++q) {
            c0[q] = __builtin_nontemporal_load(&cols[ia + q]);
            c1[q] = __builtin_nontemporal_load(&cols[ib + q]);
            v0[q] = __builtin_nontemporal_load(&vals[ia + q]);
            v1[q] = __builtin_nontemporal_load(&vals[ib + q]);
        }
#pragma unroll
        for (int q = 0; q < 4; ++q) {
            u0[q] = base[(size_t)c0[q] * 64 + lane];
            u1[q] = base[(size_t)c1[q] * 64 + lane];
        }
#pragma unroll
        for (int q = 0; q < 4; ++q) {
            axa += v0[q] * bf2f((ushort)(u0[q] & 0xffff));
            aya += v0[q] * bf2f((ushort)(u0[q] >> 16));
            axb += v1[q] * bf2f((ushort)(u1[q] & 0xffff));
            ayb += v1[q] * bf2f((ushort)(u1[q] >> 16));
        }
        ia += 4; ib += 4;
    }
    for (; ia < ea; ++ia) {
        int c = cols[ia]; float v = vals[ia];
        uint u = base[(size_t)c * 64 + lane];
        axa += v * bf2f((ushort)(u & 0xffff));
        aya += v * bf2f((ushort)(u >> 16));
    }
    for (; ib < eb; ++ib) {
        int c = cols[ib]; float v = vals[ib];
        uint u = base[(size_t)c * 64 + lane];
        axb += v * bf2f((ushort)(u & 0xffff));
        ayb += v * bf2f((ushort)(u >> 16));
    }

    f32x2 oa; oa[0] = axa; oa[1] = aya;
    __builtin_nontemporal_store(oa, (f32x2*)out + (size_t)ra * 64 + lane);
    if (has_b) {
        f32x2 ob; ob[0] = axb; ob[1] = ayb;
        __builtin_nontemporal_store(ob, (f32x2*)out + (size_t)(ra + 1) * 64 + lane);
    }
}

// ---------------------------------------------------------------------------
extern "C" void kernel_launch(void* const* d_in, const int* in_sizes, int n_in,
                              void* d_out, int out_size, void* d_ws, size_t ws_size,
                              hipStream_t stream) {
    const float* X    = (const float*)d_in[0];
    const float* W    = (const float*)d_in[1];
    const int*   rows = (const int*)d_in[2];
    const int*   cols = (const int*)d_in[3];
    const float* vals = (const float*)d_in[4];
    float*       out  = (float*)d_out;

    const int M = in_sizes[0] / D;      // 100000 nodes
    const int E = in_sizes[2];          // 1600000 edges

    // Workspace: XW bf16[M*128] | rp int[M+1] | Wf bf16[16384] | Xb bf16[M*128]
    char* ws = (char*)d_ws;
    size_t o_xw = 0;
    size_t o_rp = o_xw + (size_t)M * D * sizeof(ushort);
    size_t o_wf = (o_rp + (size_t)(M + 1) * sizeof(int) + 15) & ~(size_t)15;
    size_t o_xb = o_wf + (size_t)16384 * sizeof(ushort);
    size_t need = o_xb + (size_t)M * D * sizeof(ushort);

    ushort* XWb = (ushort*)(ws + o_xw);
    int*    rp  = (int*)(ws + o_rp);
    ushort* Wf  = (ushort*)(ws + o_wf);
    ushort* Xb  = (ushort*)(ws + o_xb);

    if (ws_size >= need) {
        const int nXchunks = M * (D / 8);                   // 8 floats/thread
        const int rowptr_blocks = (M + 256) / 256;          // covers M+1 ids
        int grid = (nXchunks + 255) / 256;
        if (grid < 64 + rowptr_blocks) grid = 64 + rowptr_blocks;
        prep<<<grid, 256, 0, stream>>>(X, W, rows, Xb, Wf, rp, M, E, nXchunks);
        gemm_lean<<<(M + 63) / 64, 256, 0, stream>>>(Xb, Wf, XWb, M);
    } else {
        gemm_fused<<<(M + 63) / 64, 256, 0, stream>>>(X, W, rows, E, XWb, rp, M);
    }
    spmm_csr<<<(M + 7) / 8, 256, 0, stream>>>(XWb, rp, cols, vals, out, M);
}